// Round 1
// baseline (880.533 us; speedup 1.0000x reference)
//
#include <hip/hip_runtime.h>

namespace {
constexpr int B = 8, C = 128, H = 160, W = 512, D = 64;
constexpr int BLK_J = 128;   // output j columns per block
constexpr int RW    = 192;   // right window cols (j0-64 .. j0+127)
constexpr int PSTR  = 133;   // P epilogue stride in floats (odd -> conflict-free scatter)
constexpr int HD    = 32;    // epilogue d-rows per pass (2 passes over d)

// LDS layout: row j holds its 32-channel chunk as 32 consecutive bf16 (64 B),
// with a 16 B skew inserted every 4 rows:
//   u16 offset(j, c) = j*32 + (j>>2)*8 + c
// Bank math (verified by enumeration):
//   - u16x4 staging writes (j = 4*lane+jj): 272 B per lane-step -> starts
//     {0,4,..,28} x 4 lanes, half-waves offset 2 banks -> 4 req/bank (min).
//   - u16x8 fragment reads (j = base+row, c = 8q): starts land 8 lanes per
//     16 B slot over all 8 slots -> 8 req/bank (min). Conflict-free.
constexpr int LSZ = (BLK_J / 4) * 136;   // 4352 u16 = 8704 B
constexpr int RSZ = (RW    / 4) * 136;   // 6528 u16 = 13056 B

typedef unsigned short u16;
typedef u16   u16x4 __attribute__((ext_vector_type(4)));
typedef u16   u16x8 __attribute__((ext_vector_type(8)));
typedef short s16x8 __attribute__((ext_vector_type(8)));
typedef float f32x4 __attribute__((ext_vector_type(4)));

__device__ inline u16 f2bf(float f) {
    unsigned u = __builtin_bit_cast(unsigned, f);
    u += 0x7fffu + ((u >> 16) & 1u);          // RNE
    return (u16)(u >> 16);
}

__device__ inline int ldso(int j, int c) { return j * 32 + (j >> 2) * 8 + c; }

union SmemU {
    struct { __align__(16) u16 L[LSZ]; __align__(16) u16 R[RSZ]; } s;  // 21760 B
    float P[HD * PSTR];                                                 // 17024 B
};

__global__ __launch_bounds__(256, 7) void cost_volume_kernel(
    const float* __restrict__ left,
    const float* __restrict__ right,
    float* __restrict__ out)
{
    __shared__ SmemU sm;

    const int jb = blockIdx.x;
    const int h  = blockIdx.y;
    const int b  = blockIdx.z;
    const int j0 = jb * BLK_J;

    const int tid  = threadIdx.x;
    const int lane = tid & 63;
    const int wv   = tid >> 6;

    const size_t cstride = (size_t)H * W;
    const float* lptr = left  + ((size_t)b * C * H + h) * W;
    const float* rptr = right + ((size_t)b * C * H + h) * W;

    // ---- staging decomposition (per thread, per 32-channel chunk) ----
    // L and R-partA: 4 float4 loads at channels cq..cq+3, cols jL..jL+3
    // R-partB:       2 float4 loads at channels cp,cp+1, cols jB..jB+3
    const int cq  = (tid >> 5) * 4;         // 0,4,...,28
    const int jL  = (tid & 31) * 4;         // 0..124
    const int cp  = (tid >> 4) * 2;         // 0,2,...,30
    const int jB  = 128 + (tid & 15) * 4;   // 128..188

    // ---- mfma fragment mapping (16x16x32): A[m=lane&15][k=(lane>>4)*8+i] ----
    const int row  = lane & 15;
    const int q    = lane >> 4;
    const int kc   = q * 8;                 // channel offset within chunk (linear)
    const int t1_0 = wv * 2;
    const int jw   = t1_0 * 16;

    f32x4 acc[2][5];
    #pragma unroll
    for (int a = 0; a < 2; ++a)
      #pragma unroll
      for (int g = 0; g < 5; ++g)
        acc[a][g] = f32x4{0.f, 0.f, 0.f, 0.f};

    f32x4 lv[4], rv[4], bv[2];
    const int gjA = j0 - 64 + jL;           // R-partA global col (may be <0 on jb==0)
    const int gjB = j0 - 64 + jB;           // R-partB global col (always >= 64)

    auto load_chunk = [&](int ch) {
        const size_t cb = (size_t)ch * 32;
        const float* lp = lptr + (cb + cq) * cstride + (j0 + jL);
        #pragma unroll
        for (int i = 0; i < 4; ++i) lv[i] = *(const f32x4*)(lp + i * cstride);
        if (gjA >= 0) {
            const float* rp = rptr + (cb + cq) * cstride + gjA;
            #pragma unroll
            for (int i = 0; i < 4; ++i) rv[i] = *(const f32x4*)(rp + i * cstride);
        } else {
            #pragma unroll
            for (int i = 0; i < 4; ++i) rv[i] = f32x4{0.f, 0.f, 0.f, 0.f};
        }
        const float* bp = rptr + (cb + cp) * cstride + gjB;
        #pragma unroll
        for (int i = 0; i < 2; ++i) bv[i] = *(const f32x4*)(bp + i * cstride);
    };

    auto write_chunk = [&]() {
        #pragma unroll
        for (int jj = 0; jj < 4; ++jj) {
            u16x4 pa, pb;
            #pragma unroll
            for (int i = 0; i < 4; ++i) pa[i] = f2bf(lv[i][jj]);
            *(u16x4*)&sm.s.L[ldso(jL + jj, cq)] = pa;
            #pragma unroll
            for (int i = 0; i < 4; ++i) pb[i] = f2bf(rv[i][jj]);
            *(u16x4*)&sm.s.R[ldso(jL + jj, cq)] = pb;
            unsigned pc = (unsigned)f2bf(bv[0][jj]) | ((unsigned)f2bf(bv[1][jj]) << 16);
            *(unsigned*)&sm.s.R[ldso(jB + jj, cp)] = pc;
        }
    };

    load_chunk(0);
    #pragma unroll
    for (int ch = 0; ch < 4; ++ch) {
        if (ch) __syncthreads();
        write_chunk();
        if (ch < 3) load_chunk(ch + 1);   // prefetch overlaps barrier + MFMA below
        __syncthreads();

        u16x8 Af[2], Bf[6];
        Af[0] = *(const u16x8*)&sm.s.L[ldso(jw      + row, kc)];
        Af[1] = *(const u16x8*)&sm.s.L[ldso(jw + 16 + row, kc)];
        #pragma unroll
        for (int u = 0; u < 6; ++u)
            Bf[u] = *(const u16x8*)&sm.s.R[ldso((t1_0 + u) * 16 + row, kc)];

        #pragma unroll
        for (int a = 0; a < 2; ++a)
          #pragma unroll
          for (int g = 0; g < 5; ++g)
            acc[a][g] = __builtin_amdgcn_mfma_f32_16x16x32_bf16(
                __builtin_bit_cast(s16x8, Af[a]),
                __builtin_bit_cast(s16x8, Bf[a + 4 - g]),
                acc[a][g], 0, 0, 0);
    }

    // ---- epilogue: 2 passes over d (halves the P overlay -> 7 blocks/CU) ----
    const float inv = 1.0f / (float)C;
    float* obase = out + (size_t)b * D * H * W + (size_t)h * W;

    __syncthreads();          // staging LDS -> P overlay
    #pragma unroll
    for (int half = 0; half < 2; ++half) {
        if (half) __syncthreads();        // stores of prev half done reading P
        const int dbase = half * HD;
        #pragma unroll
        for (int a = 0; a < 2; ++a) {
          const int t1 = t1_0 + a;
          #pragma unroll
          for (int g = 0; g < 5; ++g) {
            #pragma unroll
            for (int r = 0; r < 4; ++r) {
              const int m  = q * 4 + r;
              const int jl = t1 * 16 + m;
              const int dl = 16 * g + m - row - dbase;  // d - dbase
              if ((unsigned)dl < (unsigned)HD)
                sm.P[dl * PSTR + jl] = acc[a][g][r] * inv;
            }
          }
        }
        __syncthreads();
        #pragma unroll
        for (int s = 0; s < 4; ++s) {
            const int u  = tid + 256 * s;
            const int dl = u >> 5;
            const int j4 = (u & 31) * 4;
            f32x4 v;
            #pragma unroll
            for (int i = 0; i < 4; ++i) v[i] = sm.P[dl * PSTR + j4 + i];
            *(f32x4*)(obase + (size_t)(dbase + dl) * cstride + j0 + j4) = v;
        }
    }
}
} // namespace

extern "C" void kernel_launch(void* const* d_in, const int* in_sizes, int n_in,
                              void* d_out, int out_size, void* d_ws, size_t ws_size,
                              hipStream_t stream)
{
    const float* left  = (const float*)d_in[0];
    const float* right = (const float*)d_in[1];
    float* out = (float*)d_out;
    dim3 grid(W / BLK_J, H, B);   // (4, 160, 8) = 5120 blocks
    cost_volume_kernel<<<grid, 256, 0, stream>>>(left, right, out);
}

// Round 2
// 683.542 us; speedup vs baseline: 1.2882x; 1.2882x over previous
//
#include <hip/hip_runtime.h>

namespace {
constexpr int B = 8, C = 128, H = 160, W = 512, D = 64;
constexpr int BLK_J = 128;   // output j columns per block
constexpr int RW    = 192;   // right window cols (j0-64 .. j0+127)
constexpr int PSTR  = 133;   // P epilogue stride in floats (2-way max on scatter)

// LDS layout: row j holds its 32-channel chunk as 32 consecutive bf16 (64 B),
// with a 16 B skew inserted every 4 rows:
//   u16 offset(j, c) = j*32 + (j>>2)*8 + c
// Staging u16x4 writes and u16x8 fragment reads are bank-uniform (verified by
// enumeration: 4 req/bank on 8B writes, 8 lanes per 16B slot on reads).
constexpr int LSZ = (BLK_J / 4) * 136;   // 4352 u16 = 8704 B per buffer
constexpr int RSZ = (RW    / 4) * 136;   // 6528 u16 = 13056 B per buffer

typedef unsigned short u16;
typedef u16   u16x4 __attribute__((ext_vector_type(4)));
typedef u16   u16x8 __attribute__((ext_vector_type(8)));
typedef short s16x8 __attribute__((ext_vector_type(8)));
typedef float f32x4 __attribute__((ext_vector_type(4)));

__device__ inline u16 f2bf(float f) {
    unsigned u = __builtin_bit_cast(unsigned, f);
    u += 0x7fffu + ((u >> 16) & 1u);          // RNE
    return (u16)(u >> 16);
}

__device__ inline int ldso(int j, int c) { return j * 32 + (j >> 2) * 8 + c; }

union SmemU {
    // double-buffered staging: 43520 B total
    struct { __align__(16) u16 L[2][LSZ]; __align__(16) u16 R[2][RSZ]; } s;
    float P[D * PSTR];                        // 34048 B epilogue overlay
};

// 512 threads = 8 waves; 6 waves/EU => 3 blocks/CU (reg cap ~85, LDS 3x43.5K)
__global__ __launch_bounds__(512, 6) void cost_volume_kernel(
    const float* __restrict__ left,
    const float* __restrict__ right,
    float* __restrict__ out)
{
    __shared__ SmemU sm;

    const int jb = blockIdx.x;
    const int h  = blockIdx.y;
    const int b  = blockIdx.z;
    const int j0 = jb * BLK_J;

    const int tid  = threadIdx.x;
    const int lane = tid & 63;
    const int wv   = tid >> 6;          // 0..7

    const size_t cstride = (size_t)H * W;
    const float* lptr = left  + ((size_t)b * C * H + h) * W;
    const float* rptr = right + ((size_t)b * C * H + h) * W;

    // ---- staging role split: waves 0-3 stage L, waves 4-7 stage R ----
    // per role-thread (256 threads each), per 32-channel chunk:
    //   L:   4 float4 at channels cq..cq+3, cols jL..jL+3      (16 floats)
    //   R-A: 4 float4 at channels cq..cq+3, cols gjA..gjA+3    (16 floats)
    //   R-B: 2 float4 at channels cp,cp+1,  cols gjB..gjB+3    (+8 floats)
    const int isR = tid >> 8;               // 0 or 1
    const int t   = tid & 255;
    const int cq  = (t >> 5) * 4;           // 0,4,...,28
    const int jL  = (t & 31) * 4;           // 0..124
    const int cp  = (t >> 4) * 2;           // 0,2,...,30
    const int jB  = 128 + (t & 15) * 4;     // 128..188
    const int gjA = j0 - 64 + jL;           // may be <0 on jb==0 -> zero fill
    const int gjB = j0 - 64 + jB;           // always >= 64

    // ---- mfma fragment mapping (16x16x32): one j-tile per wave ----
    const int row = lane & 15;
    const int q   = lane >> 4;
    const int kc  = q * 8;                  // channel offset within chunk
    const int t1  = wv;                     // j-tile index 0..7

    f32x4 acc[5];
    #pragma unroll
    for (int g = 0; g < 5; ++g) acc[g] = f32x4{0.f, 0.f, 0.f, 0.f};

    f32x4 v[4], bv[2];

    auto load_chunk = [&](int ch) {
        const size_t cb = (size_t)ch * 32;
        if (!isR) {
            const float* lp = lptr + (cb + cq) * cstride + (j0 + jL);
            #pragma unroll
            for (int i = 0; i < 4; ++i) v[i] = *(const f32x4*)(lp + i * cstride);
        } else {
            if (gjA >= 0) {
                const float* rp = rptr + (cb + cq) * cstride + gjA;
                #pragma unroll
                for (int i = 0; i < 4; ++i) v[i] = *(const f32x4*)(rp + i * cstride);
            } else {
                #pragma unroll
                for (int i = 0; i < 4; ++i) v[i] = f32x4{0.f, 0.f, 0.f, 0.f};
            }
            const float* bp = rptr + (cb + cp) * cstride + gjB;
            #pragma unroll
            for (int i = 0; i < 2; ++i) bv[i] = *(const f32x4*)(bp + i * cstride);
        }
    };

    auto write_chunk = [&](int pb) {
        if (!isR) {
            #pragma unroll
            for (int jj = 0; jj < 4; ++jj) {
                u16x4 pa;
                #pragma unroll
                for (int i = 0; i < 4; ++i) pa[i] = f2bf(v[i][jj]);
                *(u16x4*)&sm.s.L[pb][ldso(jL + jj, cq)] = pa;
            }
        } else {
            #pragma unroll
            for (int jj = 0; jj < 4; ++jj) {
                u16x4 pa;
                #pragma unroll
                for (int i = 0; i < 4; ++i) pa[i] = f2bf(v[i][jj]);
                *(u16x4*)&sm.s.R[pb][ldso(jL + jj, cq)] = pa;
                unsigned pc = (unsigned)f2bf(bv[0][jj]) | ((unsigned)f2bf(bv[1][jj]) << 16);
                *(unsigned*)&sm.s.R[pb][ldso(jB + jj, cp)] = pc;
            }
        }
    };

    load_chunk(0);
    #pragma unroll
    for (int ch = 0; ch < 4; ++ch) {
        write_chunk(ch & 1);
        if (ch < 3) load_chunk(ch + 1);   // prefetch in flight across MFMA phase
        __syncthreads();                  // single barrier per chunk (dbuf)

        const u16x8 Af = *(const u16x8*)&sm.s.L[ch & 1][ldso(t1 * 16 + row, kc)];
        #pragma unroll
        for (int g = 0; g < 5; ++g) {
            const u16x8 Bf = *(const u16x8*)&sm.s.R[ch & 1][ldso((t1 + 4 - g) * 16 + row, kc)];
            acc[g] = __builtin_amdgcn_mfma_f32_16x16x32_bf16(
                __builtin_bit_cast(s16x8, Af),
                __builtin_bit_cast(s16x8, Bf),
                acc[g], 0, 0, 0);
        }
    }

    // ---- epilogue: scatter P into LDS, then coalesced float4 stores ----
    __syncthreads();          // staging LDS -> P overlay
    const float inv = 1.0f / (float)C;
    #pragma unroll
    for (int g = 0; g < 5; ++g) {
        #pragma unroll
        for (int r = 0; r < 4; ++r) {
            const int m  = q * 4 + r;
            const int jl = t1 * 16 + m;
            const int d  = 16 * g + m - row;   // d = j - j2; R zeros handle band edge
            if ((unsigned)d < (unsigned)D)
                sm.P[d * PSTR + jl] = acc[g][r] * inv;
        }
    }
    __syncthreads();

    float* obase = out + (size_t)b * D * H * W + (size_t)h * W;
    #pragma unroll
    for (int s = 0; s < 4; ++s) {
        const int u  = tid + 512 * s;
        const int d  = u >> 5;
        const int j4 = (u & 31) * 4;
        f32x4 vv;
        #pragma unroll
        for (int i = 0; i < 4; ++i) vv[i] = sm.P[d * PSTR + j4 + i];
        *(f32x4*)(obase + (size_t)d * cstride + j0 + j4) = vv;
    }
}
} // namespace

extern "C" void kernel_launch(void* const* d_in, const int* in_sizes, int n_in,
                              void* d_out, int out_size, void* d_ws, size_t ws_size,
                              hipStream_t stream)
{
    const float* left  = (const float*)d_in[0];
    const float* right = (const float*)d_in[1];
    float* out = (float*)d_out;
    dim3 grid(W / BLK_J, H, B);   // (4, 160, 8) = 5120 blocks
    cost_volume_kernel<<<grid, 512, 0, stream>>>(left, right, out);
}